// Round 1
// baseline (107.024 us; speedup 1.0000x reference)
//
#include <hip/hip_runtime.h>

// DelayedXOR SH-SNN forward.
// Key insight: s_g.reshape(B,H) maps group neuron (g,j) -> soma neuron h=g*16+j
// one-to-one, so every (b,h) chain is fully independent. One thread per chain.
//
// Correctness: spike thresholds make the recurrence bit-sensitive. All fp32
// arithmetic mirrors the reference expression order exactly, with fp contract
// OFF so no mul+add is fused into fma. Sigmoid computed in double, rounded to
// fp32 (correctly rounded).

constexpr int BATCH = 1024;
constexpr int T     = 1024;
constexpr int H     = 32;
constexpr int TDEC  = 768;   // max(T - T/4, T/2)

template <bool ACCUM>
__device__ __forceinline__ void do_step(float x0, float x1,
                                        float w0, float w1,
                                        float ag, float omg,
                                        float as, float oms,
                                        float& v, float& sf,
                                        float& V, float& Sf,
                                        float& acc)
{
#pragma clang fp contract(off)
    // v_g = alpha_g*v_g + (1-alpha_g)*gi - V_TH*s_g   (V_TH = 1.0 exact)
    float m0 = x0 * w0;
    float m1 = x1 * w1;
    float gi = m0 + m1;          // einsum over i=0,1 in index order
    float t2 = omg * gi;
    float t1 = ag * v;
    float u  = t1 + t2;
    v = u - sf;                  // sf = previous s_g in {0,1}
    bool s = v > 1.0f;           // spike(v - 1) == (v > 1) exactly in fp32
    sf = s ? 1.0f : 0.0f;
    // V = alpha_s*V + (1-alpha_s)*integ - V_TH*S ; integ = s (current step)
    float a2 = s ? oms : 0.0f;   // (1-as)*integ exact for integ in {0,1}
    float a1 = as * V;
    float a3 = a1 + a2;
    V = a3 - Sf;                 // Sf = previous S in {0,1}
    bool S = V > 1.0f;
    Sf = S ? 1.0f : 0.0f;
    if (ACCUM) acc += Sf;
}

__device__ __forceinline__ void loadv8(float* d, const float4* base, int idx4)
{
    // load 8 timesteps (16 floats) as 4x float4
#pragma unroll
    for (int i = 0; i < 4; ++i) {
        float4 t = base[idx4 + i];
        d[4*i + 0] = t.x; d[4*i + 1] = t.y; d[4*i + 2] = t.z; d[4*i + 3] = t.w;
    }
}

template <bool ACCUM>
__device__ __forceinline__ void proc8(const float* xb,
                                      float w0, float w1,
                                      float ag, float omg,
                                      float as, float oms,
                                      float& v, float& sf,
                                      float& V, float& Sf,
                                      float& acc)
{
#pragma unroll
    for (int k = 0; k < 8; ++k) {
        do_step<ACCUM>(xb[2*k], xb[2*k+1], w0, w1, ag, omg, as, oms,
                       v, sf, V, Sf, acc);
    }
}

__global__ __launch_bounds__(64) void snn_fwd(
    const float* __restrict__ x,       // [B, T, 2]
    const float* __restrict__ Wg,      // [2, 16, 2] == [h][2]
    const float* __restrict__ tau_m,   // [2, 16] == [h]
    const float* __restrict__ soma,    // [32]
    const float* __restrict__ W_out,   // [1, 32]
    const float* __restrict__ b_out,   // [1]
    float* __restrict__ out)           // [B, 1]
{
#pragma clang fp contract(off)
    const int gtid = blockIdx.x * blockDim.x + threadIdx.x;
    const int h = gtid & (H - 1);
    const int b = gtid >> 5;
    if (b >= BATCH) return;

    const float w0 = Wg[2*h + 0];
    const float w1 = Wg[2*h + 1];
    // sigmoid in double, rounded once to fp32
    const float ag  = (float)(1.0 / (1.0 + exp(-(double)tau_m[h])));
    const float omg = 1.0f - ag;
    const float as  = (float)(1.0 / (1.0 + exp(-(double)soma[h])));
    const float oms = 1.0f - as;

    const float4* __restrict__ xrow = (const float4*)(x + (size_t)b * (2 * T));

    float v = 0.f, sf = 0.f, V = 0.f, Sf = 0.f, acc = 0.f;

    float xa[16], xc[16];
    loadv8(xa, xrow, 0);                       // steps 0..7

    // phase 1: t in [0, TDEC), no accumulation. TDEC % 16 == 0.
    for (int t0 = 0; t0 < TDEC; t0 += 16) {
        loadv8(xc, xrow, (t0 + 8) >> 1);       // steps t0+8 .. t0+15
        proc8<false>(xa, w0, w1, ag, omg, as, oms, v, sf, V, Sf, acc);
        loadv8(xa, xrow, (t0 + 16) >> 1);      // steps t0+16 .. t0+23 (<= T-? ok: last loads 768..775)
        proc8<false>(xc, w0, w1, ag, omg, as, oms, v, sf, V, Sf, acc);
    }
    // phase 2: t in [TDEC, T), accumulate S. xa currently holds steps TDEC..TDEC+7.
    for (int t0 = TDEC; t0 < T; t0 += 16) {
        loadv8(xc, xrow, (t0 + 8) >> 1);
        proc8<true>(xa, w0, w1, ag, omg, as, oms, v, sf, V, Sf, acc);
        if (t0 + 16 < T)
            loadv8(xa, xrow, (t0 + 16) >> 1);
        proc8<true>(xc, w0, w1, ag, omg, as, oms, v, sf, V, Sf, acc);
    }

    // out[b] = sum_h acc[h] * W_out[h] + b_out   (reduction order slack ~1e-6,
    // far below the 3.5e-3 threshold; no nonlinearity follows)
    float val = acc * W_out[h];
#pragma unroll
    for (int m = 16; m >= 1; m >>= 1)
        val += __shfl_xor(val, m, 64);
    if ((gtid & 31) == 0)
        out[b] = val + b_out[0];
}

extern "C" void kernel_launch(void* const* d_in, const int* in_sizes, int n_in,
                              void* d_out, int out_size, void* d_ws, size_t ws_size,
                              hipStream_t stream)
{
    const float* x     = (const float*)d_in[0];
    const float* Wg    = (const float*)d_in[1];
    const float* tau_m = (const float*)d_in[2];
    const float* soma  = (const float*)d_in[3];
    const float* W_out = (const float*)d_in[4];
    const float* b_out = (const float*)d_in[5];
    float* out = (float*)d_out;

    // 512 blocks x 64 threads = 32768 threads = one (b,h) chain each.
    // Single-wave blocks spread across all 256 CUs (~2 waves/CU).
    dim3 grid((BATCH * H) / 64), block(64);
    hipLaunchKernelGGL(snn_fwd, grid, block, 0, stream,
                       x, Wg, tau_m, soma, W_out, b_out, out);
}